// Round 1
// baseline (266.157 us; speedup 1.0000x reference)
//
#include <hip/hip_runtime.h>
#include <math.h>

// Problem constants (from reference setup_inputs)
constexpr int B   = 32;
constexpr int C   = 256;
constexpr int HW  = 56 * 56;       // 3136
constexpr int HW4 = HW / 4;        // 784 float4 per (b,c) plane
constexpr int HID = 32;            // C / R, R=8
constexpr int K   = 2;
constexpr float LAMBDA_ALPHA = 1.0f;
constexpr float LAMBDA_BETA  = 0.5f;
constexpr int BDIM = 256;

// ---------------------------------------------------------------------------
// Kernel 1: per-(b,c) mean over H*W.  One block per plane, fully coalesced
// float4 reads.  pooled[b*C+c] = mean(x[b,c,:,:])
// ---------------------------------------------------------------------------
__global__ __launch_bounds__(BDIM) void pool_kernel(const float* __restrict__ x,
                                                    float* __restrict__ pooled) {
    const int bc = blockIdx.x;                       // 0 .. B*C-1
    const float4* x4 = reinterpret_cast<const float4*>(x) + (size_t)bc * HW4;

    float s = 0.0f;
    for (int t = threadIdx.x; t < HW4; t += BDIM) {
        float4 v = x4[t];
        s += (v.x + v.y) + (v.z + v.w);
    }
    // wave (64-lane) butterfly reduce
    for (int off = 32; off > 0; off >>= 1) s += __shfl_down(s, off, 64);

    __shared__ float wsum[BDIM / 64];
    const int lane = threadIdx.x & 63;
    const int wid  = threadIdx.x >> 6;
    if (lane == 0) wsum[wid] = s;
    __syncthreads();
    if (threadIdx.x == 0) {
        float tot = wsum[0] + wsum[1] + wsum[2] + wsum[3];
        pooled[bc] = tot * (1.0f / (float)HW);
    }
}

// ---------------------------------------------------------------------------
// Kernel 2: the tiny FC chain.  Single block, 256 threads.
//   h = relu(pooled @ fc1_w^T + fc1_b)                 (32 x 32)
//   delta[k,b,o] = fc2_w[k,o,:] . h[b,:] + fc2_b[k,o]  (2 x 32 x 512)
//   d = 2*sigmoid(delta) - 1
//   coef[b*C+c] = (a0, b0, a1, b1)
//     a_k = (k==0) + 1.0 * d[k,b,2c];  b_k = (k==0) + 0.5 * d[k,b,2c+1]
// ---------------------------------------------------------------------------
__global__ __launch_bounds__(BDIM) void coef_kernel(const float* __restrict__ pooled,
                                                    const float* __restrict__ fc1_w,
                                                    const float* __restrict__ fc1_b,
                                                    const float* __restrict__ fc2_w,
                                                    const float* __restrict__ fc2_b,
                                                    float4* __restrict__ coef) {
    __shared__ float hsh[B * HID];                   // 32*32 = 1024 floats
    const int tid = threadIdx.x;

    // h: 1024 outputs, 4 per thread, each a length-256 dot
    for (int i = tid; i < B * HID; i += BDIM) {
        const int b  = i >> 5;                       // / HID
        const int hh = i & (HID - 1);
        const float* pp = pooled + b * C;
        const float* pw = fc1_w + hh * C;
        float acc = fc1_b[hh];
        #pragma unroll 8
        for (int c = 0; c < C; ++c) acc = fmaf(pp[c], pw[c], acc);
        hsh[b * HID + hh] = fmaxf(acc, 0.0f);
    }
    __syncthreads();

    // coefficients: 8192 (b,c) pairs, 32 per thread, 4 length-32 dots each
    for (int i = tid; i < B * C; i += BDIM) {
        const int b = i >> 8;                        // / C
        const int c = i & (C - 1);
        const float* hp = hsh + b * HID;
        float o4[4];
        #pragma unroll
        for (int k = 0; k < K; ++k) {
            #pragma unroll
            for (int e = 0; e < 2; ++e) {
                const int o = 2 * c + e;
                const float* w2 = fc2_w + ((size_t)(k * 2 * C + o)) * HID;
                float acc = fc2_b[k * 2 * C + o];
                #pragma unroll
                for (int hh = 0; hh < HID; ++hh) acc = fmaf(w2[hh], hp[hh], acc);
                const float d = 2.0f / (1.0f + expf(-acc)) - 1.0f;
                const float init = (k == 0) ? 1.0f : 0.0f;
                o4[k * 2 + e] = init + ((e == 0) ? LAMBDA_ALPHA : LAMBDA_BETA) * d;
            }
        }
        coef[i] = make_float4(o4[0], o4[1], o4[2], o4[3]);
    }
}

// ---------------------------------------------------------------------------
// Kernel 3: out = max(x*a0 + b0, x*a1 + b1), one block per (b,c) plane.
// ---------------------------------------------------------------------------
__global__ __launch_bounds__(BDIM) void apply_kernel(const float* __restrict__ x,
                                                     const float4* __restrict__ coef,
                                                     float* __restrict__ out) {
    const int bc = blockIdx.x;
    const float4 cf = coef[bc];                      // (a0, b0, a1, b1)
    const float4* x4 = reinterpret_cast<const float4*>(x) + (size_t)bc * HW4;
    float4*       o4 = reinterpret_cast<float4*>(out) + (size_t)bc * HW4;

    for (int t = threadIdx.x; t < HW4; t += BDIM) {
        float4 v = x4[t];
        float4 r;
        r.x = fmaxf(fmaf(v.x, cf.x, cf.y), fmaf(v.x, cf.z, cf.w));
        r.y = fmaxf(fmaf(v.y, cf.x, cf.y), fmaf(v.y, cf.z, cf.w));
        r.z = fmaxf(fmaf(v.z, cf.x, cf.y), fmaf(v.z, cf.z, cf.w));
        r.w = fmaxf(fmaf(v.w, cf.x, cf.y), fmaf(v.w, cf.z, cf.w));
        o4[t] = r;
    }
}

// ---------------------------------------------------------------------------
extern "C" void kernel_launch(void* const* d_in, const int* in_sizes, int n_in,
                              void* d_out, int out_size, void* d_ws, size_t ws_size,
                              hipStream_t stream) {
    const float* x     = (const float*)d_in[0];
    const float* fc1_w = (const float*)d_in[1];
    const float* fc1_b = (const float*)d_in[2];
    const float* fc2_w = (const float*)d_in[3];
    const float* fc2_b = (const float*)d_in[4];
    float* out = (float*)d_out;

    // workspace layout: pooled (B*C floats = 32 KB) | coef (B*C float4 = 128 KB)
    float*  pooled = (float*)d_ws;
    float4* coef   = (float4*)((char*)d_ws + (size_t)B * C * sizeof(float));

    pool_kernel<<<B * C, BDIM, 0, stream>>>(x, pooled);
    coef_kernel<<<1, BDIM, 0, stream>>>(pooled, fc1_w, fc1_b, fc2_w, fc2_b, coef);
    apply_kernel<<<B * C, BDIM, 0, stream>>>(x, coef, out);
}

// Round 3
// 230.596 us; speedup vs baseline: 1.1542x; 1.1542x over previous
//
#include <hip/hip_runtime.h>
#include <math.h>

// Problem constants (from reference setup_inputs)
constexpr int B   = 32;
constexpr int C   = 256;
constexpr int HW  = 56 * 56;       // 3136
constexpr int HW4 = HW / 4;        // 784 float4 per (b,c) plane
constexpr int HID = 32;            // C / R, R=8
constexpr float LAMBDA_ALPHA = 1.0f;
constexpr float LAMBDA_BETA  = 0.5f;
constexpr int BDIM = 256;

// ---------------------------------------------------------------------------
// Kernel 1: per-(b,c) mean over H*W.  One block per plane, fully coalesced
// float4 reads.  pooled[b*C+c] = mean(x[b,c,:,:])
// ---------------------------------------------------------------------------
__global__ __launch_bounds__(BDIM) void pool_kernel(const float* __restrict__ x,
                                                    float* __restrict__ pooled) {
    const int bc = blockIdx.x;                       // 0 .. B*C-1
    const float4* x4 = reinterpret_cast<const float4*>(x) + (size_t)bc * HW4;

    float s = 0.0f;
    for (int t = threadIdx.x; t < HW4; t += BDIM) {
        float4 v = x4[t];
        s += (v.x + v.y) + (v.z + v.w);
    }
    // wave (64-lane) reduce
    for (int off = 32; off > 0; off >>= 1) s += __shfl_down(s, off, 64);

    __shared__ float wsum[BDIM / 64];
    const int lane = threadIdx.x & 63;
    const int wid  = threadIdx.x >> 6;
    if (lane == 0) wsum[wid] = s;
    __syncthreads();
    if (threadIdx.x == 0) {
        float tot = wsum[0] + wsum[1] + wsum[2] + wsum[3];
        pooled[bc] = tot * (1.0f / (float)HW);
    }
}

// ---------------------------------------------------------------------------
// Kernel 2: fc1 only.  h[b,hh] = relu(pooled[b,:] . fc1_w[hh,:] + fc1_b[hh])
// 1024 outputs, single block, float4 dot-256 each.  ~0.26 MFLOP — tiny.
// ---------------------------------------------------------------------------
__global__ __launch_bounds__(BDIM) void fc1_kernel(const float* __restrict__ pooled,
                                                   const float* __restrict__ fc1_w,
                                                   const float* __restrict__ fc1_b,
                                                   float* __restrict__ h) {
    for (int i = threadIdx.x; i < B * HID; i += BDIM) {
        const int b  = i >> 5;                       // / HID
        const int hh = i & (HID - 1);
        const float4* pp = reinterpret_cast<const float4*>(pooled + b * C);
        const float4* pw = reinterpret_cast<const float4*>(fc1_w + hh * C);
        float acc = fc1_b[hh];
        #pragma unroll
        for (int q = 0; q < C / 4; ++q) {
            float4 p = pp[q], w = pw[q];
            acc = fmaf(p.x, w.x, fmaf(p.y, w.y, fmaf(p.z, w.z, fmaf(p.w, w.w, acc))));
        }
        h[i] = fmaxf(acc, 0.0f);
    }
}

// ---------------------------------------------------------------------------
// Kernel 3: fused coef + apply.  One block per (b,c) plane.
// Coefficients (4 dot-32 over fc2_w + sigmoid) are block-uniform; every
// thread computes them redundantly (~128 FMA + 4 expf) — negligible next to
// the 24.5 KB of streaming traffic per block.
// out = max(x*a0 + b0, x*a1 + b1)
// ---------------------------------------------------------------------------
__global__ __launch_bounds__(BDIM) void apply_kernel(const float* __restrict__ x,
                                                     const float* __restrict__ h,
                                                     const float* __restrict__ fc2_w,
                                                     const float* __restrict__ fc2_b,
                                                     float* __restrict__ out) {
    const int bc = blockIdx.x;
    const int b  = bc >> 8;                          // / C
    const int c  = bc & (C - 1);

    const float4* h4 = reinterpret_cast<const float4*>(h + b * HID);
    float cf[4];                                     // a0, b0, a1, b1
    #pragma unroll
    for (int k = 0; k < 2; ++k) {
        #pragma unroll
        for (int e = 0; e < 2; ++e) {
            const int o = 2 * c + e;
            const float4* w4 = reinterpret_cast<const float4*>(
                fc2_w + (size_t)(k * 2 * C + o) * HID);
            float acc = fc2_b[k * 2 * C + o];
            #pragma unroll
            for (int q = 0; q < HID / 4; ++q) {
                float4 w = w4[q], hv = h4[q];
                acc = fmaf(w.x, hv.x, fmaf(w.y, hv.y, fmaf(w.z, hv.z, fmaf(w.w, hv.w, acc))));
            }
            const float d = 2.0f / (1.0f + expf(-acc)) - 1.0f;
            cf[k * 2 + e] = ((k == 0) ? 1.0f : 0.0f) +
                            ((e == 0) ? LAMBDA_ALPHA : LAMBDA_BETA) * d;
        }
    }

    const float4* x4 = reinterpret_cast<const float4*>(x) + (size_t)bc * HW4;
    float4*       o4 = reinterpret_cast<float4*>(out) + (size_t)bc * HW4;
    for (int t = threadIdx.x; t < HW4; t += BDIM) {
        float4 v = x4[t];
        float4 r;
        r.x = fmaxf(fmaf(v.x, cf[0], cf[1]), fmaf(v.x, cf[2], cf[3]));
        r.y = fmaxf(fmaf(v.y, cf[0], cf[1]), fmaf(v.y, cf[2], cf[3]));
        r.z = fmaxf(fmaf(v.z, cf[0], cf[1]), fmaf(v.z, cf[2], cf[3]));
        r.w = fmaxf(fmaf(v.w, cf[0], cf[1]), fmaf(v.w, cf[2], cf[3]));
        o4[t] = r;
    }
}

// ---------------------------------------------------------------------------
extern "C" void kernel_launch(void* const* d_in, const int* in_sizes, int n_in,
                              void* d_out, int out_size, void* d_ws, size_t ws_size,
                              hipStream_t stream) {
    const float* x     = (const float*)d_in[0];
    const float* fc1_w = (const float*)d_in[1];
    const float* fc1_b = (const float*)d_in[2];
    const float* fc2_w = (const float*)d_in[3];
    const float* fc2_b = (const float*)d_in[4];
    float* out = (float*)d_out;

    // workspace layout: pooled (B*C floats = 32 KB) | h (B*HID floats = 4 KB)
    float* pooled = (float*)d_ws;
    float* h      = pooled + (size_t)B * C;

    pool_kernel<<<B * C, BDIM, 0, stream>>>(x, pooled);
    fc1_kernel<<<1, BDIM, 0, stream>>>(pooled, fc1_w, fc1_b, h);
    apply_kernel<<<B * C, BDIM, 0, stream>>>(x, h, fc2_w, fc2_b, out);
}